// Round 4
// baseline (8175.082 us; speedup 1.0000x reference)
//
#include <hip/hip_runtime.h>

// ---------------- problem constants ----------------
#define BB 256   // batch
#define TT 256   // time steps
#define II 16    // input dim (layer 0)
#define HH 512   // hidden
#define G4 2048  // 4*H
#define LL 4     // layers

typedef float f32x4 __attribute__((ext_vector_type(4)));
typedef _Float16 f16x8 __attribute__((ext_vector_type(8)));
typedef _Float16 f16x4 __attribute__((ext_vector_type(4)));
typedef float f32x4v __attribute__((ext_vector_type(4)));
typedef unsigned int u32x4 __attribute__((ext_vector_type(4)));

#define MFMA16(a, b, c) __builtin_amdgcn_mfma_f32_16x16x32_f16((a), (b), (c), 0, 0, 0)

// ---------------- static device state ----------------
// exchange buffer: [l][g][t][jc][row(32)][col(16)] f16 — each block's slice is 1KB contiguous
__device__ _Float16 g_hx[(size_t)LL * 8 * TT * 32 * 32 * 16];
__device__ _Float16 g_xbf[(size_t)BB * TT * II];
__device__ _Float16 g_wih0[G4 * II];
__device__ _Float16 g_whh[(size_t)LL * G4 * HH];
__device__ _Float16 g_wihr[(size_t)3 * G4 * HH];
__device__ float    g_bias[LL * G4];
__device__ unsigned g_flag[256 * 16];   // (g*32+jc) -> slot at *16 (64B stride)

// ---------------- helpers ----------------
__device__ __forceinline__ unsigned ld_cv32(const unsigned* p) {
  unsigned r;
  asm volatile("global_load_dword %0, %1, off sc0 sc1\n\ts_waitcnt vmcnt(0)"
               : "=v"(r) : "v"(p) : "memory");
  return r;
}
__device__ __forceinline__ void st_cv32(unsigned* p, unsigned v) {
  asm volatile("global_store_dword %0, %1, off sc0 sc1" : : "v"(p), "v"(v) : "memory");
}
__device__ __forceinline__ void st_cv16(void* p, u32x4 v) {
  asm volatile("global_store_dwordx4 %0, %1, off sc0 sc1" : : "v"(p), "v"(v) : "memory");
}
__device__ __forceinline__ float fsig(float x) { return 1.f / (1.f + __expf(-x)); }
__device__ __forceinline__ float ftanh(float x) { return 1.f - 2.f / (__expf(2.f * x) + 1.f); }

// A-fragment read from swizzled LDS tile [32][512] f16
__device__ __forceinline__ f16x8 ldsA(const _Float16* base, int mt, int kt, int lane) {
  int row = mt * 16 + (lane & 15);
  int off = (row << 10) + (kt << 6) + ((lane >> 4) << 4);
  off ^= (lane & 15) << 4;
  return *(const f16x8*)((const char*)base + off);
}

// ---------------- prep ----------------
__device__ __forceinline__ void cv4(_Float16* d, const float* s, size_t n4, size_t tid, size_t stride) {
  for (size_t i = tid; i < n4; i += stride) {
    f32x4v v = ((const f32x4v*)s)[i];
    ((f16x4*)d)[i] = __builtin_convertvector(v, f16x4);
  }
}

__global__ void prep_kernel(const float* __restrict__ x, const float* __restrict__ wih0,
                            const float* __restrict__ whh0, const float* __restrict__ bih0,
                            const float* __restrict__ bhh0, const float* __restrict__ wihr,
                            const float* __restrict__ whhr, const float* __restrict__ bihr,
                            const float* __restrict__ bhhr) {
  size_t tid = (size_t)blockIdx.x * blockDim.x + threadIdx.x;
  size_t stride = (size_t)gridDim.x * blockDim.x;
  cv4(g_xbf, x, (size_t)BB * TT * II / 4, tid, stride);
  cv4(g_wih0, wih0, (size_t)G4 * II / 4, tid, stride);
  cv4(g_whh, whh0, (size_t)G4 * HH / 4, tid, stride);
  cv4(g_whh + (size_t)G4 * HH, whhr, (size_t)3 * G4 * HH / 4, tid, stride);
  cv4(g_wihr, wihr, (size_t)3 * G4 * HH / 4, tid, stride);
  for (size_t i = tid; i < G4; i += stride) g_bias[i] = bih0[i] + bhh0[i];
  for (size_t i = tid; i < 3 * G4; i += stride) g_bias[G4 + i] = bihr[i] + bhhr[i];
  for (size_t i = tid; i < 256; i += stride) st_cv32(&g_flag[i * 16], 0u);
}

// ---------------- persistent LSTM kernel, 2-group alternation ----------------
// 128 blocks x 256 threads. jc = bid>>2 (h-cols [16jc,16jc+16)); groups {bid&3, (bid&3)+4}.
// Per (l,t): section A then section B. While A's flag/data propagate through LLC, the
// block computes B's step. Weights (same jc) shared by both groups; xs/hs/gbuf/hout shared.
__global__ __launch_bounds__(256, 1) void lstm_kernel() {
  const int tid = threadIdx.x;
  const int jc = blockIdx.x >> 2;
  const int gA = blockIdx.x & 3;
  const int w = tid >> 6;
  const int lane = tid & 63;
  const int col = lane & 15, kg = lane >> 4;
  const int n0 = w * 512 + jc * 16;

  __shared__ _Float16 xs[32 * 512];
  __shared__ _Float16 hs[32 * 512];
  __shared__ float gbuf[4][32 * 17];
  __shared__ unsigned hout[32][8];

  const int eb = tid >> 3;      // elementwise: batch row 0..31
  const int ej2 = tid & 7;      // elementwise: col-pair index 0..7

  f16x8 wihf[16], whhf[16];
  u32x4 vx[2][8], vx0[2];
  float c0[2], c1[2];
  const int gArr[2] = {gA, gA + 4};

  // one-time zero-pad of xs byte-cols [32,64) (layer 0's K=16..31)
  if (tid < 64) {
    int row = tid >> 1, part = tid & 1;
    int off = (row << 10) + 32 + (part << 4); off ^= (row & 15) << 4;
    u32x4 z = {0u, 0u, 0u, 0u};
    *(u32x4*)((char*)xs + off) = z;
  }
  // pre-load x_0 (layer 0) for both groups
#pragma unroll
  for (int sg = 0; sg < 2; ++sg) {
    if (tid < 64) {
      int row = tid >> 1, part = tid & 1;
      vx0[sg] = *(const u32x4*)(g_xbf + ((size_t)(32 * gArr[sg] + row) * TT) * II + part * 8);
    }
  }

  for (int l = 0; l < LL; ++l) {
    // ---- per-layer weight fragments (shared by both groups) ----
    {
      const _Float16* wb = g_whh + ((size_t)l * G4 + (n0 + col)) * HH + kg * 8;
#pragma unroll
      for (int kt = 0; kt < 16; ++kt) whhf[kt] = *(const f16x8*)(wb + kt * 32);
      if (l == 0) {
        if (kg < 2) wihf[0] = *(const f16x8*)(g_wih0 + (n0 + col) * II + kg * 8);
        else { f16x8 z = {}; wihf[0] = z; }
      } else {
        const _Float16* wi = g_wihr + ((size_t)(l - 1) * G4 + (n0 + col)) * HH + kg * 8;
#pragma unroll
        for (int kt = 0; kt < 16; ++kt) wihf[kt] = *(const f16x8*)(wi + kt * 32);
      }
    }
    const float bias = g_bias[l * G4 + n0 + col];
#pragma unroll
    for (int sg = 0; sg < 2; ++sg) { c0[sg] = 0.f; c1[sg] = 0.f; }

    for (int t = 0; t < TT; ++t) {
#pragma unroll
      for (int sg = 0; sg < 2; ++sg) {
        const int g = gArr[sg];
        const size_t blobL = ((size_t)l * 8 + g) * TT;          // blob index base (x16384 elems)

        // ---- poll: all 32 blocks of group g completed (l,t-1) ----
        const unsigned tgt = (unsigned)(l * TT + t);
        if (tgt && tid < 64) {
          const unsigned* fp = &g_flag[(g * 32 + (tid & 31)) * 16];
          while (ld_cv32(fp) < tgt) {}
        }
        __syncthreads();

        // ---- layer boundary: load x_0 post-poll ----
        if (t == 0 && l > 0) {
          const char* xb = (const char*)(g_hx + (((size_t)(l - 1) * 8 + g) * TT) * 16384);
#pragma unroll
          for (int it = 0; it < 8; ++it)
            vx[sg][it] = *(const u32x4*)(xb + tid * 16 + it * 4096);
        }
        // ---- issue h_{t-1} loads (plain cached; coalesced 32KB blob) ----
        u32x4 vh[8];
        if (t > 0) {
          const char* hb = (const char*)(g_hx + (blobL + (t - 1)) * 16384);
#pragma unroll
          for (int it = 0; it < 8; ++it)
            vh[it] = *(const u32x4*)(hb + tid * 16 + it * 4096);
        }
        // ---- stage xs (swizzled) ----
        if (l > 0) {
#pragma unroll
          for (int it = 0; it < 8; ++it) {
            int jcs = (tid >> 6) + it * 4, row = (tid >> 1) & 31, p = tid & 1;
            int off = (row << 10) + jcs * 32 + (p << 4); off ^= (row & 15) << 4;
            *(u32x4*)((char*)xs + off) = vx[sg][it];
          }
        } else if (tid < 64) {
          int row = tid >> 1, part = tid & 1;
          int off = (row << 10) + (part << 4); off ^= (row & 15) << 4;
          *(u32x4*)((char*)xs + off) = vx0[sg];
        }
        __syncthreads();

        // ---- x-GEMM (h loads in flight) ----
        f32x4 a0 = {bias, bias, bias, bias}, a1 = a0;
        if (l == 0) {
          a0 = MFMA16(ldsA(xs, 0, 0, lane), wihf[0], a0);
          a1 = MFMA16(ldsA(xs, 1, 0, lane), wihf[0], a1);
        } else {
#pragma unroll
          for (int kt = 0; kt < 16; ++kt) {
            a0 = MFMA16(ldsA(xs, 0, kt, lane), wihf[kt], a0);
            a1 = MFMA16(ldsA(xs, 1, kt, lane), wihf[kt], a1);
          }
        }

        // ---- stage hs ----
        if (t > 0) {
#pragma unroll
          for (int it = 0; it < 8; ++it) {
            int jcs = (tid >> 6) + it * 4, row = (tid >> 1) & 31, p = tid & 1;
            int off = (row << 10) + jcs * 32 + (p << 4); off ^= (row & 15) << 4;
            *(u32x4*)((char*)hs + off) = vh[it];
          }
          __syncthreads();
        }
        // ---- prefetch x_{t+1} (old data; overlaps h-GEMM + epilogue) ----
        if (t + 1 < TT) {
          if (l > 0) {
            const char* xb = (const char*)(g_hx + (((size_t)(l - 1) * 8 + g) * TT + (t + 1)) * 16384);
#pragma unroll
            for (int it = 0; it < 8; ++it)
              vx[sg][it] = *(const u32x4*)(xb + tid * 16 + it * 4096);
          } else if (tid < 64) {
            int row = tid >> 1, part = tid & 1;
            vx0[sg] = *(const u32x4*)(g_xbf + ((size_t)(32 * g + row) * TT + (t + 1)) * II + part * 8);
          }
        }
        // ---- h-GEMM ----
        if (t > 0) {
#pragma unroll
          for (int kt = 0; kt < 16; ++kt) {
            a0 = MFMA16(ldsA(hs, 0, kt, lane), whhf[kt], a0);
            a1 = MFMA16(ldsA(hs, 1, kt, lane), whhf[kt], a1);
          }
        }

        // ---- publish gate tiles ----
#pragma unroll
        for (int r = 0; r < 4; ++r) {
          gbuf[w][(kg * 4 + r) * 17 + col] = a0[r];
          gbuf[w][(16 + kg * 4 + r) * 17 + col] = a1[r];
        }
        __syncthreads();

        // ---- elementwise LSTM cell, pack h pair into hout ----
        {
          int i0 = eb * 17 + ej2 * 2;
          float i_0 = fsig(gbuf[0][i0]),  i_1 = fsig(gbuf[0][i0 + 1]);
          float f_0 = fsig(gbuf[1][i0]),  f_1 = fsig(gbuf[1][i0 + 1]);
          float t_0 = ftanh(gbuf[2][i0]), t_1 = ftanh(gbuf[2][i0 + 1]);
          float o_0 = fsig(gbuf[3][i0]),  o_1 = fsig(gbuf[3][i0 + 1]);
          c0[sg] = f_0 * c0[sg] + i_0 * t_0;
          c1[sg] = f_1 * c1[sg] + i_1 * t_1;
          float h0 = o_0 * ftanh(c0[sg]), h1 = o_1 * ftanh(c1[sg]);
          _Float16 hh0 = (_Float16)h0, hh1 = (_Float16)h1;
          hout[eb][ej2] = ((unsigned)__builtin_bit_cast(unsigned short, hh1) << 16) |
                          (unsigned)__builtin_bit_cast(unsigned short, hh0);
        }
        __syncthreads();

        // ---- store 1KB slice (wave 0 only: 64 x dwordx4), drain, signal ----
        if (tid < 64) {
          int row = tid >> 1, part = tid & 1;
          u32x4 v = *(const u32x4*)&hout[row][part * 4];
          _Float16* dst = g_hx + ((blobL + t) * 32 + jc) * 512 + row * 16 + part * 8;
          st_cv16(dst, v);
          asm volatile("s_waitcnt vmcnt(0)" ::: "memory");
          if (tid == 0) st_cv32(&g_flag[(g * 32 + jc) * 16], (unsigned)(l * TT + t + 1));
        }
      }  // sg
    }    // t
  }      // l
}

// ---------------- FC head ----------------
__global__ void fc_kernel(const float* __restrict__ fcw, const float* __restrict__ fcb,
                          float* __restrict__ out) {
  int b = blockIdx.x, lane = threadIdx.x;
  int g = b >> 5, row = b & 31;
  int jcs = lane >> 1, part = lane & 1;
  const _Float16* h = g_hx + ((((size_t)3 * 8 + g) * TT + (TT - 1)) * 32 + jcs) * 512 + row * 16 + part * 8;
  f16x8 hv = *(const f16x8*)h;
  const float* wp = fcw + lane * 8;
  float s = 0.f;
#pragma unroll
  for (int j = 0; j < 8; ++j) s += (float)hv[j] * wp[j];
#pragma unroll
  for (int off = 32; off; off >>= 1) s += __shfl_down(s, off, 64);
  if (lane == 0) out[b] = 1.f / (1.f + __expf(-(s + fcb[0])));
}

// ---------------- launch ----------------
extern "C" void kernel_launch(void* const* d_in, const int* in_sizes, int n_in,
                              void* d_out, int out_size, void* d_ws, size_t ws_size,
                              hipStream_t stream) {
  const float* x    = (const float*)d_in[0];
  const float* wih0 = (const float*)d_in[1];
  const float* whh0 = (const float*)d_in[2];
  const float* bih0 = (const float*)d_in[3];
  const float* bhh0 = (const float*)d_in[4];
  const float* wihr = (const float*)d_in[5];
  const float* whhr = (const float*)d_in[6];
  const float* bihr = (const float*)d_in[7];
  const float* bhhr = (const float*)d_in[8];
  const float* fcw  = (const float*)d_in[9];
  const float* fcb  = (const float*)d_in[10];

  prep_kernel<<<dim3(1024), dim3(256), 0, stream>>>(x, wih0, whh0, bih0, bhh0,
                                                    wihr, whhr, bihr, bhhr);
  lstm_kernel<<<dim3(128), dim3(256), 0, stream>>>();
  fc_kernel<<<dim3(256), dim3(64), 0, stream>>>(fcw, fcb, (float*)d_out);
}

// Round 6
// 4089.941 us; speedup vs baseline: 1.9988x; 1.9988x over previous
//
#include <hip/hip_runtime.h>

// ---------------- problem constants ----------------
#define BB 256   // batch
#define TT 256   // time steps
#define II 16    // input dim (layer 0)
#define HH 512   // hidden
#define G4 2048  // 4*H
#define LL 4     // layers
#define POISON 0xFFFFFFFFu   // f16 pair = (-NaN,-NaN): unreachable for h = o*tanh(c)

typedef float f32x4 __attribute__((ext_vector_type(4)));
typedef _Float16 f16x8 __attribute__((ext_vector_type(8)));
typedef _Float16 f16x4 __attribute__((ext_vector_type(4)));
typedef float f32x4v __attribute__((ext_vector_type(4)));
typedef unsigned int u32x4 __attribute__((ext_vector_type(4)));

#define MFMA16(a, b, c) __builtin_amdgcn_mfma_f32_16x16x32_f16((a), (b), (c), 0, 0, 0)

// ---------------- static device state ----------------
__device__ _Float16 g_hbuf[(size_t)LL * BB * TT * HH];   // h per layer, poisoned each launch
__device__ _Float16 g_xbf[(size_t)BB * TT * II];         // x in f16
__device__ _Float16 g_wih0[G4 * II];
__device__ _Float16 g_whh[(size_t)LL * G4 * HH];
__device__ _Float16 g_wihr[(size_t)3 * G4 * HH];
__device__ float    g_bias[LL * G4];

// ---------------- asm memory helpers (all in-loop VMEM is inline asm -> exact vmcnt) ----
__device__ __forceinline__ u32x4 ld_cv(const void* p) {   // LLC-coherent bypass load
  u32x4 r;
  asm volatile("global_load_dwordx4 %0, %1, off sc0 sc1" : "=v"(r) : "v"(p) : "memory");
  return r;
}
__device__ __forceinline__ u32x4 ld_nc(const void* p) {   // normal cached load (untracked)
  u32x4 r;
  asm volatile("global_load_dwordx4 %0, %1, off" : "=v"(r) : "v"(p) : "memory");
  return r;
}
__device__ __forceinline__ void st_cv(void* p, unsigned v) {  // write-through store
  asm volatile("global_store_dword %0, %1, off sc0 sc1" : : "v"(p), "v"(v) : "memory");
}
#define WAITV0() asm volatile("s_waitcnt vmcnt(0)" ::: "memory")
#define WAITV1() asm volatile("s_waitcnt vmcnt(1)" ::: "memory")

__device__ __forceinline__ float fsig(float x) { return 1.f / (1.f + __expf(-x)); }
__device__ __forceinline__ float ftanh(float x) { return 1.f - 2.f / (__expf(2.f * x) + 1.f); }
__device__ __forceinline__ unsigned max4u(u32x4 v) {
  unsigned a = v[0] > v[1] ? v[0] : v[1];
  unsigned b = v[2] > v[3] ? v[2] : v[3];
  return a > b ? a : b;
}

// A-fragment read from swizzled LDS tile [32][512] f16 (round-3 proven layout)
__device__ __forceinline__ f16x8 ldsA(const _Float16* base, int mt, int kt, int lane) {
  int row = mt * 16 + (lane & 15);
  int off = (row << 10) + (kt << 6) + ((lane >> 4) << 4);
  off ^= (lane & 15) << 4;
  return *(const f16x8*)((const char*)base + off);
}

// ---------------- prep: conversions, bias sums, h-buffer poison ----------------
__device__ __forceinline__ void cv4(_Float16* d, const float* s, size_t n4, size_t tid, size_t stride) {
  for (size_t i = tid; i < n4; i += stride) {
    f32x4v v = ((const f32x4v*)s)[i];
    ((f16x4*)d)[i] = __builtin_convertvector(v, f16x4);
  }
}

__global__ void prep_kernel(const float* __restrict__ x, const float* __restrict__ wih0,
                            const float* __restrict__ whh0, const float* __restrict__ bih0,
                            const float* __restrict__ bhh0, const float* __restrict__ wihr,
                            const float* __restrict__ whhr, const float* __restrict__ bihr,
                            const float* __restrict__ bhhr) {
  size_t tid = (size_t)blockIdx.x * blockDim.x + threadIdx.x;
  size_t stride = (size_t)gridDim.x * blockDim.x;
  cv4(g_xbf, x, (size_t)BB * TT * II / 4, tid, stride);
  cv4(g_wih0, wih0, (size_t)G4 * II / 4, tid, stride);
  cv4(g_whh, whh0, (size_t)G4 * HH / 4, tid, stride);
  cv4(g_whh + (size_t)G4 * HH, whhr, (size_t)3 * G4 * HH / 4, tid, stride);
  cv4(g_wihr, wihr, (size_t)3 * G4 * HH / 4, tid, stride);
  for (size_t i = tid; i < G4; i += stride) g_bias[i] = bih0[i] + bhh0[i];
  for (size_t i = tid; i < 3 * G4; i += stride) g_bias[G4 + i] = bihr[i] + bhhr[i];
  // poison the whole h exchange buffer (each launch): data-embedded readiness
  u32x4 P = {POISON, POISON, POISON, POISON};
  size_t n16 = (size_t)LL * BB * TT * HH * 2 / 16;
  u32x4* hb = (u32x4*)g_hbuf;
  for (size_t i = tid; i < n16; i += stride) hb[i] = P;
}

// ---------------- persistent LSTM kernel (flagless data-poll) ----------------
// 256 blocks x 256 threads, 1 block/CU. group g = bid&7 owns batch rows [32g,32g+32);
// block jc = bid>>3 owns h-cols [16jc,16jc+16). Producers fire-and-forget h stores;
// consumers validate loaded h/x against POISON per wave and retry via LLC-bypass loads.
__global__ __launch_bounds__(256, 1) void lstm_kernel() {
  const int tid = threadIdx.x;
  const int g = blockIdx.x & 7;
  const int jc = blockIdx.x >> 3;
  const int w = tid >> 6;
  const int lane = tid & 63;
  const int col = lane & 15, kg = lane >> 4;
  const int n0 = w * 512 + jc * 16;

  __shared__ _Float16 xs[32 * 512];
  __shared__ _Float16 hs[32 * 512];
  __shared__ float gbuf[4][32 * 17];

  const int eb = tid >> 3;        // elementwise: batch row 0..31
  const int ej = (tid & 7) * 2;   // elementwise: h-col pair

  f16x8 wihf[16], whhf[16];

  // one-time zero-pad of xs byte-cols [32,64) (layer 0's K=16..31)
  if (tid < 64) {
    int row = tid >> 1, half = tid & 1;
    int off = (row << 10) + 32 + (half << 4); off ^= (row & 15) << 4;
    u32x4 z = {0u, 0u, 0u, 0u};
    *(u32x4*)((char*)xs + off) = z;
  }

  for (int l = 0; l < LL; ++l) {
    // ---- per-layer: weight fragments into registers (pre-loop, compiler-tracked) ----
    {
      const _Float16* wb = g_whh + ((size_t)l * G4 + (n0 + col)) * HH + kg * 8;
#pragma unroll
      for (int kt = 0; kt < 16; ++kt) whhf[kt] = *(const f16x8*)(wb + kt * 32);
      if (l == 0) {
        if (kg < 2) wihf[0] = *(const f16x8*)(g_wih0 + (n0 + col) * II + kg * 8);
        else { f16x8 z = {}; wihf[0] = z; }
      } else {
        const _Float16* wi = g_wihr + ((size_t)(l - 1) * G4 + (n0 + col)) * HH + kg * 8;
#pragma unroll
        for (int kt = 0; kt < 16; ++kt) wihf[kt] = *(const f16x8*)(wi + kt * 32);
      }
    }
    const float bias = g_bias[l * G4 + n0 + col];
    float c0 = 0.f, c1 = 0.f;

    const _Float16* xsrc = g_hbuf + ((size_t)(l - 1) * BB + 32 * g) * TT * HH;  // l>0
    _Float16* hdst = g_hbuf + ((size_t)l * BB + 32 * g) * TT * HH;

    // ---- prologue: issue x_0 loads ----
    u32x4 vx[8], vx0;
    if (l > 0) {
#pragma unroll
      for (int it = 0; it < 8; ++it) {
        int q = tid + it * 256, row = q >> 6, c16 = q & 63;
        vx[it] = ld_nc((const char*)(xsrc + (size_t)row * TT * HH) + c16 * 16);
      }
    } else if (tid < 64) {
      int row = tid >> 1, half = tid & 1;
      vx0 = ld_nc(g_xbf + ((size_t)(32 * g + row) * TT) * II + half * 8);
    }

    for (int t = 0; t < TT; ++t) {
      // ---- A) wait x regs (vmcnt(1): h-store may still fly; t==0 drains all) ----
      if (t == 0) WAITV0(); else WAITV1();
      if (l > 0) {
        // validate + retry (per-wave; x slices of lagging producers may be poison)
        while (true) {
          unsigned mx = 0u;
#pragma unroll
          for (int it = 0; it < 8; ++it) { unsigned m = max4u(vx[it]); mx = mx > m ? mx : m; }
          if (!__any((int)(mx == POISON))) break;
#pragma unroll
          for (int it = 0; it < 8; ++it) {
            int q = tid + it * 256, row = q >> 6, c16 = q & 63;
            vx[it] = ld_cv((const char*)(xsrc + (size_t)t * HH + (size_t)row * TT * HH) + c16 * 16);
          }
          WAITV0();
        }
        // stage xs (swizzled)
#pragma unroll
        for (int it = 0; it < 8; ++it) {
          int q = tid + it * 256, row = q >> 6, c16 = q & 63;
          int off = (row << 10) + (c16 << 4); off ^= (row & 15) << 4;
          *(u32x4*)((char*)xs + off) = vx[it];
        }
      } else if (tid < 64) {
        int row = tid >> 1, half = tid & 1;
        int off = (row << 10) + (half << 4); off ^= (row & 15) << 4;
        *(u32x4*)((char*)xs + off) = vx0;
      }

      // ---- B) issue h_{t-1} loads (LLC-coherent; flight covered by barrier + x-GEMM) ----
      u32x4 vh[8];
      if (t > 0) {
        const _Float16* sh = hdst + (size_t)(t - 1) * HH;
#pragma unroll
        for (int it = 0; it < 8; ++it) {
          int q = tid + it * 256, row = q >> 6, c16 = q & 63;
          vh[it] = ld_cv((const char*)(sh + (size_t)row * TT * HH) + c16 * 16);
        }
      }
      __syncthreads();   // xs ready

      // ---- C) x-GEMM ----
      f32x4 a0 = {bias, bias, bias, bias}, a1 = a0;
      if (l == 0) {
        a0 = MFMA16(ldsA(xs, 0, 0, lane), wihf[0], a0);
        a1 = MFMA16(ldsA(xs, 1, 0, lane), wihf[0], a1);
      } else {
#pragma unroll
        for (int kt = 0; kt < 16; ++kt) {
          a0 = MFMA16(ldsA(xs, 0, kt, lane), wihf[kt], a0);
          a1 = MFMA16(ldsA(xs, 1, kt, lane), wihf[kt], a1);
        }
      }

      // ---- D) h: wait + validate + stage ----
      if (t > 0) {
        WAITV0();
        while (true) {
          unsigned mx = 0u;
#pragma unroll
          for (int it = 0; it < 8; ++it) { unsigned m = max4u(vh[it]); mx = mx > m ? mx : m; }
          if (!__any((int)(mx == POISON))) break;
          const _Float16* sh = hdst + (size_t)(t - 1) * HH;
#pragma unroll
          for (int it = 0; it < 8; ++it) {
            int q = tid + it * 256, row = q >> 6, c16 = q & 63;
            vh[it] = ld_cv((const char*)(sh + (size_t)row * TT * HH) + c16 * 16);
          }
          WAITV0();
        }
#pragma unroll
        for (int it = 0; it < 8; ++it) {
          int q = tid + it * 256, row = q >> 6, c16 = q & 63;
          int off = (row << 10) + (c16 << 4); off ^= (row & 15) << 4;
          *(u32x4*)((char*)hs + off) = vh[it];
        }
        __syncthreads();
      }

      // ---- E) prefetch x_{t+1} (issued BEFORE h-store so A's vmcnt(1) counts right) ----
      if (t + 1 < TT) {
        if (l > 0) {
          const _Float16* sx = xsrc + (size_t)(t + 1) * HH;
#pragma unroll
          for (int it = 0; it < 8; ++it) {
            int q = tid + it * 256, row = q >> 6, c16 = q & 63;
            vx[it] = ld_nc((const char*)(sx + (size_t)row * TT * HH) + c16 * 16);
          }
        } else if (tid < 64) {
          int row = tid >> 1, half = tid & 1;
          vx0 = ld_nc(g_xbf + ((size_t)(32 * g + row) * TT + (t + 1)) * II + half * 8);
        }
      }

      // ---- F) h-GEMM ----
      if (t > 0) {
#pragma unroll
        for (int kt = 0; kt < 16; ++kt) {
          a0 = MFMA16(ldsA(hs, 0, kt, lane), whhf[kt], a0);
          a1 = MFMA16(ldsA(hs, 1, kt, lane), whhf[kt], a1);
        }
      }

      // ---- G) publish gate tiles ----
#pragma unroll
      for (int r = 0; r < 4; ++r) {
        gbuf[w][(kg * 4 + r) * 17 + col] = a0[r];
        gbuf[w][(16 + kg * 4 + r) * 17 + col] = a1[r];
      }
      __syncthreads();

      // ---- H) elementwise cell; fire-and-forget h store (no drain, no flag) ----
      {
        int i0 = eb * 17 + ej;
        float i_0 = fsig(gbuf[0][i0]),  i_1 = fsig(gbuf[0][i0 + 1]);
        float f_0 = fsig(gbuf[1][i0]),  f_1 = fsig(gbuf[1][i0 + 1]);
        float t_0 = ftanh(gbuf[2][i0]), t_1 = ftanh(gbuf[2][i0 + 1]);
        float o_0 = fsig(gbuf[3][i0]),  o_1 = fsig(gbuf[3][i0 + 1]);
        c0 = f_0 * c0 + i_0 * t_0;
        c1 = f_1 * c1 + i_1 * t_1;
        float h0 = o_0 * ftanh(c0), h1 = o_1 * ftanh(c1);
        _Float16 hh0 = (_Float16)h0, hh1 = (_Float16)h1;
        unsigned pv = ((unsigned)__builtin_bit_cast(unsigned short, hh1) << 16) |
                      (unsigned)__builtin_bit_cast(unsigned short, hh0);
        st_cv(hdst + ((size_t)eb * TT + t) * HH + jc * 16 + ej, pv);
      }
    }
  }
}

// ---------------- FC head ----------------
__global__ void fc_kernel(const float* __restrict__ fcw, const float* __restrict__ fcb,
                          float* __restrict__ out) {
  int b = blockIdx.x, lane = threadIdx.x;
  const _Float16* h = g_hbuf + ((size_t)3 * BB + b) * TT * HH + (size_t)(TT - 1) * HH + lane * 8;
  f16x8 hv = *(const f16x8*)h;
  const float* wp = fcw + lane * 8;
  float s = 0.f;
#pragma unroll
  for (int j = 0; j < 8; ++j) s += (float)hv[j] * wp[j];
#pragma unroll
  for (int off = 32; off; off >>= 1) s += __shfl_down(s, off, 64);
  if (lane == 0) out[b] = 1.f / (1.f + __expf(-(s + fcb[0])));
}

// ---------------- launch ----------------
extern "C" void kernel_launch(void* const* d_in, const int* in_sizes, int n_in,
                              void* d_out, int out_size, void* d_ws, size_t ws_size,
                              hipStream_t stream) {
  const float* x    = (const float*)d_in[0];
  const float* wih0 = (const float*)d_in[1];
  const float* whh0 = (const float*)d_in[2];
  const float* bih0 = (const float*)d_in[3];
  const float* bhh0 = (const float*)d_in[4];
  const float* wihr = (const float*)d_in[5];
  const float* whhr = (const float*)d_in[6];
  const float* bihr = (const float*)d_in[7];
  const float* bhhr = (const float*)d_in[8];
  const float* fcw  = (const float*)d_in[9];
  const float* fcb  = (const float*)d_in[10];

  prep_kernel<<<dim3(1024), dim3(256), 0, stream>>>(x, wih0, whh0, bih0, bhh0,
                                                    wihr, whhr, bihr, bhhr);
  lstm_kernel<<<dim3(256), dim3(256), 0, stream>>>();
  fc_kernel<<<dim3(256), dim3(64), 0, stream>>>(fcw, fcb, (float*)d_out);
}